// Round 12
// baseline (147.368 us; speedup 1.0000x reference)
//
#include <hip/hip_runtime.h>
#include <math.h>

#define NS 512
#define NU 32
#define ND 512
#define GEPS 1e-6f

typedef float f4 __attribute__((ext_vector_type(4)));
typedef _Float16 half8 __attribute__((ext_vector_type(8)));

// ws layout: bpk[32*16*1024] f16 (1 MiB) | cn2[NS] | dn2[NS*NU] | apk[NS*2*16*1024] f16 (33.5 MiB)
// bpk chunk (ct_g, t): 1024 halves [hi 512 | lo 512], elem l*8+j = cent[col=ct_g*16+(l&15)][k=t*32+(l>>4)*8+j]
// apk chunk (s, rt, t): 1024 halves [hi 512 | lo 512], elem l*8+j = dvec[s][row=rt*16+(l&15)][k=t*32+(l>>4)*8+j]

// prep_apk: grid NS*2, block (s, rt). 4 waves; wave w packs chunks tk=w*4..w*4+3.
// One coalesced-line pass over 16 rows; dn2 via 2 shfls + LDS combine.
__global__ __launch_bounds__(256) void prep_apk(const float* __restrict__ dvecs,
                                                float* __restrict__ dn2,
                                                _Float16* __restrict__ apk) {
    const int b = blockIdx.x, s = b >> 1, rt = b & 1;
    const int t = threadIdx.x, l = t & 63, w = t >> 6, l15 = l & 15, lg = l >> 4;
    const int u = rt * 16 + l15;
    const float* rowp = dvecs + ((size_t)s * NU + u) * ND;
    __shared__ float dn2p[4][16];

    float q = 0.f;
    #pragma unroll
    for (int i = 0; i < 4; ++i) {
        const int tk = w * 4 + i;
        const int k0 = tk * 32 + lg * 8;
        f4 a0 = *(const f4*)(rowp + k0);
        f4 a1 = *(const f4*)(rowp + k0 + 4);
        q += a0[0]*a0[0] + a0[1]*a0[1] + a0[2]*a0[2] + a0[3]*a0[3]
           + a1[0]*a1[0] + a1[1]*a1[1] + a1[2]*a1[2] + a1[3]*a1[3];
        half8 h, lo;
        #pragma unroll
        for (int c = 0; c < 4; ++c) {
            _Float16 h0 = (_Float16)a0[c];
            h[c]     = h0; lo[c]     = (_Float16)(a0[c] - (float)h0);
            _Float16 h1 = (_Float16)a1[c];
            h[4 + c] = h1; lo[4 + c] = (_Float16)(a1[c] - (float)h1);
        }
        _Float16* cb = apk + ((size_t)(s * 2 + rt) * 16 + tk) * 1024 + l * 8;
        *(half8*)cb         = h;
        *(half8*)(cb + 512) = lo;
    }
    q += __shfl_xor(q, 16);
    q += __shfl_xor(q, 32);
    if (lg == 0) dn2p[w][l15] = q;
    __syncthreads();
    if (t < 16)
        dn2[s * NU + rt * 16 + t] = dn2p[0][t] + dn2p[1][t] + dn2p[2][t] + dn2p[3][t];
}

// prep_cent: verified R2/R4 centroid pattern + byte-identical bpk scatter.
__global__ __launch_bounds__(256) void prep_cent(const float* __restrict__ dvecs,
                                                 _Float16* __restrict__ bpk,
                                                 float* __restrict__ cn2) {
    const int s = blockIdx.x, t = threadIdx.x;
    const float* base = dvecs + (size_t)s * NU * ND;
    const int d0 = t * 2;
    float sx = 0.f, sy = 0.f;
    #pragma unroll 4
    for (int u = 0; u < NU; ++u) {
        float2 v = *(const float2*)(base + u * ND + d0);
        sx += v.x; sy += v.y;
    }
    sx *= (1.0f / NU); sy *= (1.0f / NU);
    float c2 = sx * sx + sy * sy;
    #pragma unroll
    for (int m = 1; m < 64; m <<= 1) c2 += __shfl_xor(c2, m);
    __shared__ float red[4];
    if ((t & 63) == 0) red[t >> 6] = c2;
    __syncthreads();
    if (t == 0) cn2[s] = red[0] + red[1] + red[2] + red[3];

    _Float16 hx = (_Float16)sx, hy = (_Float16)sy;
    _Float16 lx = (_Float16)(sx - (float)hx), ly = (_Float16)(sy - (float)hy);
    const int ct_g = s >> 4, cl15 = s & 15;
    const int tt = d0 >> 5, blg = (d0 >> 3) & 3, j = d0 & 7;   // j even
    size_t hbase = ((size_t)(ct_g * 16 + tt)) * 1024 + (blg * 16 + cl15) * 8 + j;
    unsigned hi2 = (unsigned)__builtin_bit_cast(unsigned short, hx)
                 | ((unsigned)__builtin_bit_cast(unsigned short, hy) << 16);
    unsigned lo2 = (unsigned)__builtin_bit_cast(unsigned short, lx)
                 | ((unsigned)__builtin_bit_cast(unsigned short, ly) << 16);
    *(unsigned*)(bpk + hbase)       = hi2;
    *(unsigned*)(bpk + hbase + 512) = lo2;
}

// ge2e v5: R9 tiling (grid NS, 8 waves, wave owns 64 cols) + explicit B
// double-buffer ping-pong so L2 latency hides under the MFMA clusters.
__global__ __launch_bounds__(512, 4) void ge2e_full(const _Float16* __restrict__ apk,
                                                    const _Float16* __restrict__ bpk,
                                                    const float* __restrict__ cn2,
                                                    const float* __restrict__ dn2,
                                                    const float* __restrict__ wp,
                                                    const float* __restrict__ bp,
                                                    float* __restrict__ out) {
    const int s = blockIdx.x, tid = threadIdx.x;
    const int l = tid & 63;
    const int wv = __builtin_amdgcn_readfirstlane(tid >> 6);
    const int l15 = l & 15, lg = l >> 4;

    f4 acc[2][4];
    #pragma unroll
    for (int rt = 0; rt < 2; ++rt)
        #pragma unroll
        for (int ct = 0; ct < 4; ++ct) acc[rt][ct] = (f4){0.f, 0.f, 0.f, 0.f};

    const _Float16* Au = apk + (size_t)s * 32 * 1024;
    const _Float16* Bu = bpk + (size_t)(wv * 4) * 16 * 1024;
    const int voff = l * 8;

    half8 bh0[4], bl0[4], bh1[4], bl1[4];
    #pragma unroll
    for (int ct = 0; ct < 4; ++ct) {
        const _Float16* p = Bu + (ct * 16 + 0) * 1024 + voff;
        bh0[ct] = *(const half8*)p;
        bl0[ct] = *(const half8*)(p + 512);
    }

    #pragma unroll
    for (int tt = 0; tt < 8; ++tt) {
        const int t0 = tt * 2, t1 = t0 + 1;
        // prefetch B(t1) while computing with b*0
        #pragma unroll
        for (int ct = 0; ct < 4; ++ct) {
            const _Float16* p = Bu + (ct * 16 + t1) * 1024 + voff;
            bh1[ct] = *(const half8*)p;
            bl1[ct] = *(const half8*)(p + 512);
        }
        {
            half8 ah[2], al[2];
            #pragma unroll
            for (int rt = 0; rt < 2; ++rt) {
                const _Float16* p = Au + (rt * 16 + t0) * 1024 + voff;
                ah[rt] = *(const half8*)p;
                al[rt] = *(const half8*)(p + 512);
            }
            __builtin_amdgcn_s_setprio(1);
            #pragma unroll
            for (int ct = 0; ct < 4; ++ct)
                #pragma unroll
                for (int rt = 0; rt < 2; ++rt) {
                    acc[rt][ct] = __builtin_amdgcn_mfma_f32_16x16x32_f16(ah[rt], bh0[ct], acc[rt][ct], 0, 0, 0);
                    acc[rt][ct] = __builtin_amdgcn_mfma_f32_16x16x32_f16(ah[rt], bl0[ct], acc[rt][ct], 0, 0, 0);
                    acc[rt][ct] = __builtin_amdgcn_mfma_f32_16x16x32_f16(al[rt], bh0[ct], acc[rt][ct], 0, 0, 0);
                    acc[rt][ct] = __builtin_amdgcn_mfma_f32_16x16x32_f16(al[rt], bl0[ct], acc[rt][ct], 0, 0, 0);
                }
            __builtin_amdgcn_s_setprio(0);
        }
        if (tt < 7) {
            // prefetch B(t0+2) while computing with b*1
            #pragma unroll
            for (int ct = 0; ct < 4; ++ct) {
                const _Float16* p = Bu + (ct * 16 + t0 + 2) * 1024 + voff;
                bh0[ct] = *(const half8*)p;
                bl0[ct] = *(const half8*)(p + 512);
            }
        }
        {
            half8 ah[2], al[2];
            #pragma unroll
            for (int rt = 0; rt < 2; ++rt) {
                const _Float16* p = Au + (rt * 16 + t1) * 1024 + voff;
                ah[rt] = *(const half8*)p;
                al[rt] = *(const half8*)(p + 512);
            }
            __builtin_amdgcn_s_setprio(1);
            #pragma unroll
            for (int ct = 0; ct < 4; ++ct)
                #pragma unroll
                for (int rt = 0; rt < 2; ++rt) {
                    acc[rt][ct] = __builtin_amdgcn_mfma_f32_16x16x32_f16(ah[rt], bh1[ct], acc[rt][ct], 0, 0, 0);
                    acc[rt][ct] = __builtin_amdgcn_mfma_f32_16x16x32_f16(ah[rt], bl1[ct], acc[rt][ct], 0, 0, 0);
                    acc[rt][ct] = __builtin_amdgcn_mfma_f32_16x16x32_f16(al[rt], bh1[ct], acc[rt][ct], 0, 0, 0);
                    acc[rt][ct] = __builtin_amdgcn_mfma_f32_16x16x32_f16(al[rt], bl1[ct], acc[rt][ct], 0, 0, 0);
                }
            __builtin_amdgcn_s_setprio(0);
        }
    }

    __shared__ float sDn2[32], sSelf[32], sMax[8][32], sSum[8][32], sRow[32];
    if (tid < 32) sDn2[tid] = dn2[s * NU + tid];
    __syncthreads();

    const float w = wp[0], bb = bp[0];
    const float cn2s = cn2[s];
    float dv[2][4];
    #pragma unroll
    for (int rt = 0; rt < 2; ++rt)
        #pragma unroll
        for (int r = 0; r < 4; ++r) dv[rt][r] = sDn2[rt * 16 + lg * 4 + r];

    const bool owner = (wv == (s >> 6)) && (l15 == (s & 15));
    const int  ctd   = (s >> 4) & 3;

    float dotc[2][4];
    #pragma unroll
    for (int ct = 0; ct < 4; ++ct)
        if (ct == ctd)
            #pragma unroll
            for (int rt = 0; rt < 2; ++rt)
                #pragma unroll
                for (int r = 0; r < 4; ++r) dotc[rt][r] = acc[rt][ct][r];

    #pragma unroll
    for (int ct = 0; ct < 4; ++ct) {
        const float cv = cn2[wv * 64 + ct * 16 + l15];
        #pragma unroll
        for (int rt = 0; rt < 2; ++rt)
            #pragma unroll
            for (int r = 0; r < 4; ++r)
                acc[rt][ct][r] = w * (acc[rt][ct][r] / fmaxf(sqrtf(dv[rt][r] * cv), GEPS)) + bb;
    }
    if (owner) {
        #pragma unroll
        for (int rt = 0; rt < 2; ++rt)
            #pragma unroll
            for (int r = 0; r < 4; ++r) {
                const float d2  = dv[rt][r];
                const float num = (float)NU * dotc[rt][r] - d2;
                const float X   = (float)(NU * NU) * cn2s - 2.0f * NU * dotc[rt][r] + d2;
                const float den = fmaxf(sqrtf(d2) * sqrtf(X), GEPS * (NU - 1));
                const float ls  = w * (num / den) + bb;
                #pragma unroll
                for (int ct = 0; ct < 4; ++ct)
                    if (ct == ctd) acc[rt][ct][r] = ls;
                sSelf[rt * 16 + lg * 4 + r] = ls;
            }
    }

    #pragma unroll
    for (int rt = 0; rt < 2; ++rt)
        #pragma unroll
        for (int r = 0; r < 4; ++r) {
            float mx = -INFINITY;
            #pragma unroll
            for (int ct = 0; ct < 4; ++ct) mx = fmaxf(mx, acc[rt][ct][r]);
            mx = fmaxf(mx, __shfl_xor(mx, 1)); mx = fmaxf(mx, __shfl_xor(mx, 2));
            mx = fmaxf(mx, __shfl_xor(mx, 4)); mx = fmaxf(mx, __shfl_xor(mx, 8));
            float se = 0.f;
            #pragma unroll
            for (int ct = 0; ct < 4; ++ct) se += expf(acc[rt][ct][r] - mx);
            se += __shfl_xor(se, 1); se += __shfl_xor(se, 2);
            se += __shfl_xor(se, 4); se += __shfl_xor(se, 8);
            if (l15 == 0) {
                sMax[wv][rt * 16 + lg * 4 + r] = mx;
                sSum[wv][rt * 16 + lg * 4 + r] = se;
            }
        }
    __syncthreads();

    if (tid < 32) {
        float M = -INFINITY;
        #pragma unroll
        for (int v = 0; v < 8; ++v) M = fmaxf(M, sMax[v][tid]);
        float S = 0.f;
        #pragma unroll
        for (int v = 0; v < 8; ++v) S += sSum[v][tid] * expf(sMax[v][tid] - M);
        sRow[tid] = logf(S) + M - sSelf[tid];
    }
    __syncthreads();
    if (tid == 0) {
        float tot = 0.f;
        #pragma unroll
        for (int u2 = 0; u2 < 32; ++u2) tot += sRow[u2];
        atomicAdd(out, tot);
    }
}

extern "C" void kernel_launch(void* const* d_in, const int* in_sizes, int n_in,
                              void* d_out, int out_size, void* d_ws, size_t ws_size,
                              hipStream_t stream) {
    const float* dvecs = (const float*)d_in[0];
    const float* w     = (const float*)d_in[1];
    const float* b     = (const float*)d_in[2];
    float* out = (float*)d_out;

    const size_t bpk_b = (size_t)32 * 16 * 1024 * sizeof(_Float16);     // 1 MiB
    const size_t cn2_b = (size_t)NS * sizeof(float);
    const size_t dn2_b = (size_t)NS * NU * sizeof(float);

    char* p = (char*)d_ws;
    _Float16* bpk = (_Float16*)p;                 p += bpk_b;
    float*    cn2 = (float*)p;                    p += cn2_b;
    float*    dn2 = (float*)p;                    p += dn2_b;
    _Float16* apk = (_Float16*)p;

    hipMemsetAsync(d_out, 0, sizeof(float), stream);
    prep_apk<<<NS * 2, 256, 0, stream>>>(dvecs, dn2, apk);
    prep_cent<<<NS, 256, 0, stream>>>(dvecs, bpk, cn2);
    ge2e_full<<<NS, 512, 0, stream>>>(apk, bpk, cn2, dn2, w, b, out);
}